// Round 1
// 350.165 us; speedup vs baseline: 1.0384x; 1.0384x over previous
//
#include <hip/hip_runtime.h>
#include <hip/hip_bf16.h>
#include <math.h>

#define DIM 64
#define CODES 512
#define TOKENS 262144
#define XELEMS 16777216

#define DECAYF 0.99f
#define OMDECAY 0.01f
#define EPSF 1e-5f

// workspace float offsets
#define WS_CNORM 0            // 512
#define WS_NI    512          // 512
#define WS_EOFX  1024         // 32768
#define WS_LOSS  33792        // 16
#define WS_ET    33808        // 32768 fp32 eT [512][64]
#define WS_IMG   66576        // 32768 floats = 128 KB bf16 hi/lo B image
#define WS_PART  99344        // 512 partials * PART_STRIDE
#define PART_STRIDE 33280
#define NPART 512

// output float offsets (reference return order)
#define OFF_Q    0
#define OFF_QL   16777216
#define OFF_IDX  16777217
#define OFF_CL   17039361
#define OFF_ENEW 17039362
#define OFF_NNEW 17072130
#define OFF_MNEW 17072642

typedef __attribute__((ext_vector_type(8))) short bf16x8;
typedef __attribute__((ext_vector_type(4))) float f32x4;

// Truncation hi/lo split: hi = top 16 bits, lo = top 16 bits of (v - hi).
static __device__ inline void split_bf(float v, short& hi, short& lo) {
  unsigned int b = __float_as_uint(v);
  unsigned int hb = b & 0xffff0000u;
  float lof = v - __uint_as_float(hb);
  hi = (short)(b >> 16);
  lo = (short)(__float_as_uint(lof) >> 16);
}

// Prep: thread per code. eT fp32 rows, cnorm, and the B image:
// [cc(32)][kh(2)][hi|lo][lane(64)*8] shorts (128 KB).
__global__ __launch_bounds__(256) void vq_prep(const float* __restrict__ emb,
                                               float* __restrict__ ws) {
  int c = blockIdx.x * 256 + threadIdx.x;  // 0..511
  unsigned short* img = (unsigned short*)(ws + WS_IMG);
  float* eT = ws + WS_ET;
  int cc = c >> 4;
  int n = c & 15;
  float cn = 0.f;
#pragma unroll
  for (int d0 = 0; d0 < DIM; d0 += 4) {
    float v[4];
#pragma unroll
    for (int u = 0; u < 4; ++u) {
      v[u] = emb[(d0 + u) * CODES + c];
      cn = fmaf(v[u], v[u], cn);
    }
    *(float4*)(eT + (size_t)c * DIM + d0) = make_float4(v[0], v[1], v[2], v[3]);
    int kh = d0 >> 5, kk = d0 & 31, qd = kk >> 3, j0 = kk & 7;
    int lane = qd * 16 + n;
    short hi[4], lo[4];
#pragma unroll
    for (int u = 0; u < 4; ++u) split_bf(v[u], hi[u], lo[u]);
    int base = cc * 2048 + kh * 1024 + lane * 8 + j0;
    *(ushort4*)(img + base) =
        make_ushort4((unsigned short)hi[0], (unsigned short)hi[1],
                     (unsigned short)hi[2], (unsigned short)hi[3]);
    *(ushort4*)(img + base + 512) =
        make_ushort4((unsigned short)lo[0], (unsigned short)lo[1],
                     (unsigned short)lo[2], (unsigned short)lo[3]);
  }
  ws[WS_CNORM + c] = cn;
}

// Fused screen + resolve + segment-sum. Block = 8 waves x 64 tokens.
// Occupancy-first rework vs prior version:
//  - B image read straight from global/L2 (register ping-pong prefetch),
//    no 128 KB LDS image -> LDS drops to ~72 KB -> 2 blocks/CU (4 waves/SIMD).
//  - Phase 1 runs in two tile-PAIRS (32 A-frag VGPRs live instead of 64) so
//    the kernel fits <=128 VGPR at __launch_bounds__(512, 4).
//  - Phase 2 scatters in two kh-halves into a [32][513] LDS tile (65.7 KB),
//    re-reading x from global (L3-resident) instead of rebuilding from regs.
__global__ __launch_bounds__(512, 4) void vq_fused(
    const float* __restrict__ x, const float* __restrict__ ws,
    float* __restrict__ loss_sum, float* __restrict__ q_out,
    float* __restrict__ idx_out, float* __restrict__ part_base, int aflush,
    float* __restrict__ ws_acc) {
  __shared__ __align__(16) unsigned char smem[71808];
  float* lds_e = (float*)smem;              // [32][513] phase-2 tile, 65664 B
  float* lds_n = (float*)(smem + 65664);    // 512 counts
  float* cn_l = (float*)(smem + 67712);     // 512 code norms
  int* win_l = (int*)(smem + 69760);        // 512 winner codes

  const float* eT = ws + WS_ET;
  const unsigned short* gimg = (const unsigned short*)(ws + WS_IMG);

  {
    // zero phase-2 tile + counts up front (LDS idle during phase 1), load cn
    float4 z = make_float4(0.f, 0.f, 0.f, 0.f);
    float4* zp = (float4*)smem;
    for (int i = threadIdx.x; i < 67712 / 16; i += 512) zp[i] = z;
    for (int i = threadIdx.x; i < CODES; i += 512) cn_l[i] = ws[WS_CNORM + i];
  }
  __syncthreads();

  const int lane = threadIdx.x & 63;
  const int wave = threadIdx.x >> 6;
  const int n = lane & 15;
  const int quad = lane >> 4;
  const int t0 = blockIdx.x * 512 + wave * 64;

  const float INITP = __uint_as_float((__float_as_uint(1e30f) & 0xFFFFFE00u) | 511u);
  float loss = 0.f;

#pragma unroll 1
  for (int pair = 0; pair < 2; ++pair) {
    // A-fragments hi/lo of -2x for this pair's 2 token tiles
    bf16x8 ah[2][2], al[2][2];
#pragma unroll
    for (int tile = 0; tile < 2; ++tile) {
      const float* xr =
          x + (size_t)(t0 + (pair * 2 + tile) * 16 + n) * DIM + quad * 8;
#pragma unroll
      for (int kh = 0; kh < 2; ++kh) {
        float4 va = *(const float4*)(xr + kh * 32);
        float4 vb = *(const float4*)(xr + kh * 32 + 4);
        float f[8] = {va.x, va.y, va.z, va.w, vb.x, vb.y, vb.z, vb.w};
#pragma unroll
        for (int j = 0; j < 8; ++j) {
          short hi, lo;
          split_bf(-2.f * f[j], hi, lo);
          ah[tile][kh][j] = hi;
          al[tile][kh][j] = lo;
        }
      }
    }

    // packed (value|idx) top-2 registers
    float v1[2][4], v2[2][4];
#pragma unroll
    for (int tile = 0; tile < 2; ++tile)
#pragma unroll
      for (int r = 0; r < 4; ++r) {
        v1[tile][r] = INITP;
        v2[tile][r] = INITP;
      }

    // B fragments: register ping-pong, prefetch distance 1 (from L2)
    bf16x8 Pa0, Pa1, Pa2, Pa3, Pb0, Pb1, Pb2, Pb3;
    {
      const unsigned short* bq = gimg + lane * 8;
      Pa0 = *(const bf16x8*)(bq);
      Pa1 = *(const bf16x8*)(bq + 512);
      Pa2 = *(const bf16x8*)(bq + 1024);
      Pa3 = *(const bf16x8*)(bq + 1536);
    }

    auto ccbody = [&](int cc, const bf16x8& ch0, const bf16x8& cl0,
                      const bf16x8& ch1, const bf16x8& cl1, bf16x8& nh0,
                      bf16x8& nl0, bf16x8& nh1, bf16x8& nl1) {
      // prefetch next cc's fragments (wraps harmlessly on the last iter)
      const unsigned short* bq = gimg + ((cc + 1) & 31) * 2048 + lane * 8;
      nh0 = *(const bf16x8*)(bq);
      nl0 = *(const bf16x8*)(bq + 512);
      nh1 = *(const bf16x8*)(bq + 1024);
      nl1 = *(const bf16x8*)(bq + 1536);
      float cnv = cn_l[cc * 16 + n];
      unsigned int cid = (unsigned int)(cc * 16 + n);
#pragma unroll
      for (int tile = 0; tile < 2; ++tile) {
        f32x4 acc = {0.f, 0.f, 0.f, 0.f};
        acc = __builtin_amdgcn_mfma_f32_16x16x32_bf16(ah[tile][0], ch0, acc, 0, 0, 0);
        acc = __builtin_amdgcn_mfma_f32_16x16x32_bf16(al[tile][0], ch0, acc, 0, 0, 0);
        acc = __builtin_amdgcn_mfma_f32_16x16x32_bf16(ah[tile][0], cl0, acc, 0, 0, 0);
        acc = __builtin_amdgcn_mfma_f32_16x16x32_bf16(ah[tile][1], ch1, acc, 0, 0, 0);
        acc = __builtin_amdgcn_mfma_f32_16x16x32_bf16(al[tile][1], ch1, acc, 0, 0, 0);
        acc = __builtin_amdgcn_mfma_f32_16x16x32_bf16(ah[tile][1], cl1, acc, 0, 0, 0);
#pragma unroll
        for (int r = 0; r < 4; ++r) {
          float s = acc[r] + cnv;
          float sp = __uint_as_float((__float_as_uint(s) & 0xFFFFFE00u) | cid);
          float o1 = v1[tile][r];
          v2[tile][r] = __builtin_amdgcn_fmed3f(sp, o1, v2[tile][r]);
          v1[tile][r] = fminf(sp, o1);
        }
      }
    };

    for (int cc = 0; cc < 32; cc += 2) {
      ccbody(cc, Pa0, Pa1, Pa2, Pa3, Pb0, Pb1, Pb2, Pb3);
      ccbody(cc + 1, Pb0, Pb1, Pb2, Pb3, Pa0, Pa1, Pa2, Pa3);
    }

    // butterfly top-2 merge across the quad's 16 lanes (packed floats)
#pragma unroll
    for (int m = 1; m < 16; m <<= 1) {
#pragma unroll
      for (int tile = 0; tile < 2; ++tile)
#pragma unroll
        for (int r = 0; r < 4; ++r) {
          float o1 = __shfl_xor(v1[tile][r], m, 16);
          float o2 = __shfl_xor(v2[tile][r], m, 16);
          float a = v1[tile][r];
          v1[tile][r] = fminf(a, o1);
          v2[tile][r] = fminf(fminf(v2[tile][r], o2), fmaxf(a, o1));
        }
    }

    // Exact fp32 epilogue for this pair's 2 tiles
#pragma unroll
    for (int tile = 0; tile < 2; ++tile) {
      int tt = pair * 2 + tile;
#pragma unroll
      for (int r = 0; r < 4; ++r) {
        int t = t0 + tt * 16 + quad * 4 + r;
        int c1 = (int)(__float_as_uint(v1[tile][r]) & 511u);
        int c2 = (int)(__float_as_uint(v2[tile][r]) & 511u);
        float4 xv = *(const float4*)(x + (size_t)t * DIM + n * 4);
        float4 e1 = *(const float4*)(eT + (size_t)c1 * DIM + n * 4);
        float4 e2 = *(const float4*)(eT + (size_t)c2 * DIM + n * 4);
        float p1 = xv.x * e1.x;
        p1 = fmaf(xv.y, e1.y, p1);
        p1 = fmaf(xv.z, e1.z, p1);
        p1 = fmaf(xv.w, e1.w, p1);
        float p2 = xv.x * e2.x;
        p2 = fmaf(xv.y, e2.y, p2);
        p2 = fmaf(xv.z, e2.z, p2);
        p2 = fmaf(xv.w, e2.w, p2);
#pragma unroll
        for (int m = 1; m < 16; m <<= 1) {
          p1 += __shfl_xor(p1, m, 16);
          p2 += __shfl_xor(p2, m, 16);
        }
        float d1 = fmaf(-2.f, p1, cn_l[c1]);
        float d2 = fmaf(-2.f, p2, cn_l[c2]);
        bool take2 = (d2 < d1) || (d2 == d1 && c2 < c1);
        int w = take2 ? c2 : c1;
        float4 q = take2 ? e2 : e1;
        *(float4*)(q_out + (size_t)t * DIM + n * 4) = q;
        float u0 = xv.x - q.x, u1 = xv.y - q.y;
        float u2 = xv.z - q.z, u3 = xv.w - q.w;
        loss = fmaf(u0, u0, loss);
        loss = fmaf(u1, u1, loss);
        loss = fmaf(u2, u2, loss);
        loss = fmaf(u3, u3, loss);
        if (n == 0) {
          idx_out[t] = (float)w;
          win_l[wave * 64 + tt * 16 + quad * 4 + r] = w;
        }
      }
    }
  }

#pragma unroll
  for (int off = 32; off > 0; off >>= 1) loss += __shfl_down(loss, off, 64);
  if (lane == 0) atomicAdd(loss_sum, loss);

  // ---- Phase 2: segment sum over this block's 512 tokens, kh-halves ----
  __syncthreads();  // tile pre-zeroed; win_l complete

#pragma unroll 1
  for (int kh = 0; kh < 2; ++kh) {
#pragma unroll
    for (int tile = 0; tile < 4; ++tile) {
      int wbi = win_l[wave * 64 + tile * 16 + n];
      if (kh == 0 && quad == 0) atomicAdd(&lds_n[wbi], 1.0f);
      const float* xr =
          x + (size_t)(t0 + tile * 16 + n) * DIM + kh * 32 + quad * 8;
      float4 xa = *(const float4*)(xr);
      float4 xb = *(const float4*)(xr + 4);
      int k0 = quad * 8;
      atomicAdd(&lds_e[(k0 + 0) * 513 + wbi], xa.x);
      atomicAdd(&lds_e[(k0 + 1) * 513 + wbi], xa.y);
      atomicAdd(&lds_e[(k0 + 2) * 513 + wbi], xa.z);
      atomicAdd(&lds_e[(k0 + 3) * 513 + wbi], xa.w);
      atomicAdd(&lds_e[(k0 + 4) * 513 + wbi], xb.x);
      atomicAdd(&lds_e[(k0 + 5) * 513 + wbi], xb.y);
      atomicAdd(&lds_e[(k0 + 6) * 513 + wbi], xb.z);
      atomicAdd(&lds_e[(k0 + 7) * 513 + wbi], xb.w);
    }
    __syncthreads();
    if (aflush) {
      if (kh == 0) {
        for (int i = threadIdx.x; i < CODES; i += 512) {
          float v = lds_n[i];
          if (v != 0.f) atomicAdd(&ws_acc[WS_NI + i], v);
        }
      }
      for (int i = threadIdx.x; i < 32 * CODES; i += 512) {
        int k = i >> 9, c = i & 511;
        float v = lds_e[k * 513 + c];
        if (v != 0.f) atomicAdd(&ws_acc[WS_EOFX + kh * 32 * CODES + i], v);
        if (kh == 0) lds_e[k * 513 + c] = 0.f;  // re-zero for the kh=1 pass
      }
    } else {
      float* dest = part_base + (size_t)blockIdx.x * PART_STRIDE;
      if (kh == 0) {
        for (int i = threadIdx.x; i < CODES; i += 512) dest[i] = lds_n[i];
      }
      for (int i = threadIdx.x; i < 32 * CODES; i += 512) {
        int k = i >> 9, c = i & 511;
        dest[CODES + kh * 32 * CODES + i] = lds_e[k * 513 + c];
        if (kh == 0) lds_e[k * 513 + c] = 0.f;  // re-zero for the kh=1 pass
      }
    }
    if (kh == 0) __syncthreads();
  }
}

// Deterministic reduction of NPART partials -> ws[WS_NI ..]
__global__ __launch_bounds__(256) void vq_reduce(const float* __restrict__ part,
                                                 float* __restrict__ ws, int P) {
  int i = blockIdx.x * 256 + threadIdx.x;
  if (i >= PART_STRIDE) return;
  float a0 = 0.f, a1 = 0.f, a2 = 0.f, a3 = 0.f;
  int p = 0;
  for (; p + 3 < P; p += 4) {
    a0 += part[(size_t)(p + 0) * PART_STRIDE + i];
    a1 += part[(size_t)(p + 1) * PART_STRIDE + i];
    a2 += part[(size_t)(p + 2) * PART_STRIDE + i];
    a3 += part[(size_t)(p + 3) * PART_STRIDE + i];
  }
  for (; p < P; ++p) a0 += part[(size_t)p * PART_STRIDE + i];
  ws[WS_NI + i] = (a0 + a1) + (a2 + a3);
}

// EMA update + losses. Grid = DIM blocks, one thread per code.
__global__ __launch_bounds__(512) void vq_final(const float* __restrict__ Nin,
                                                const float* __restrict__ Min,
                                                const float* __restrict__ ws,
                                                float* __restrict__ out) {
  __shared__ float red[512];
  int c = threadIdx.x;
  int d = blockIdx.x;
  float niv = ws[WS_NI + c];
  float Nn = Nin[c] * DECAYF + OMDECAY * niv;
  red[c] = Nn;
  __syncthreads();
#pragma unroll
  for (int s = 256; s > 0; s >>= 1) {
    if (c < s) red[c] += red[c + s];
    __syncthreads();
  }
  float nsum = red[0];
  float Nsm = (Nn + EPSF) / (nsum + (float)CODES * EPSF) * nsum;
  float m = Min[d * CODES + c] * DECAYF + OMDECAY * ws[WS_EOFX + d * CODES + c];
  out[OFF_MNEW + d * CODES + c] = m;
  out[OFF_ENEW + d * CODES + c] = m / Nsm;
  if (d == 0) {
    out[OFF_NNEW + c] = Nn;
    if (c == 0) {
      float l = ws[WS_LOSS] / (float)XELEMS;
      out[OFF_QL] = l;
      out[OFF_CL] = l;
    }
  }
}

extern "C" void kernel_launch(void* const* d_in, const int* in_sizes, int n_in,
                              void* d_out, int out_size, void* d_ws, size_t ws_size,
                              hipStream_t stream) {
  const float* x = (const float*)d_in[0];
  const float* emb = (const float*)d_in[1];
  const float* Nin = (const float*)d_in[2];
  const float* Min = (const float*)d_in[3];
  float* out = (float*)d_out;
  float* ws = (float*)d_ws;

  size_t avail = ws_size / 4;
  int aflush = (avail < (size_t)WS_PART + (size_t)NPART * PART_STRIDE) ? 1 : 0;

  // zero ni/eofx/loss (loss always needed; ni/eofx needed for aflush path)
  hipMemsetAsync(ws + WS_NI, 0, (size_t)(WS_ET - WS_NI) * sizeof(float), stream);

  vq_prep<<<2, 256, 0, stream>>>(emb, ws);

  vq_fused<<<TOKENS / 512, 512, 0, stream>>>(
      x, ws, ws + WS_LOSS, out + OFF_Q, out + OFF_IDX, ws + WS_PART, aflush, ws);

  if (!aflush) {
    vq_reduce<<<(PART_STRIDE + 255) / 256, 256, 0, stream>>>(ws + WS_PART, ws,
                                                             NPART);
  }

  vq_final<<<DIM, 512, 0, stream>>>(Nin, Min, ws, out);
}

// Round 2
// 311.647 us; speedup vs baseline: 1.1667x; 1.1236x over previous
//
#include <hip/hip_runtime.h>
#include <hip/hip_bf16.h>
#include <math.h>

#define DIM 64
#define CODES 512
#define TOKENS 262144
#define XELEMS 16777216

#define DECAYF 0.99f
#define OMDECAY 0.01f
#define EPSF 1e-5f

// workspace float offsets
#define WS_CNORM 0            // 512
#define WS_NI    512          // 512
#define WS_EOFX  1024         // 32768
#define WS_LOSS  33792        // 16
#define WS_ET    33808        // 32768 fp32 eT [512][64]
#define WS_IMG   66576        // 32768 floats = 128 KB bf16 hi/lo B image
#define WS_PART  99344        // 512 partials * PART_STRIDE
#define PART_STRIDE 33280
#define NPART 512

// output float offsets (reference return order)
#define OFF_Q    0
#define OFF_QL   16777216
#define OFF_IDX  16777217
#define OFF_CL   17039361
#define OFF_ENEW 17039362
#define OFF_NNEW 17072130
#define OFF_MNEW 17072642

typedef __attribute__((ext_vector_type(8))) short bf16x8;
typedef __attribute__((ext_vector_type(4))) float f32x4;

// async 16B/lane global->LDS copy: per-lane global src, wave-uniform LDS base
#define GLOAD_LDS16(gp, lp)                                        \
  __builtin_amdgcn_global_load_lds(                                \
      (const __attribute__((address_space(1))) void*)(gp),         \
      (__attribute__((address_space(3))) void*)(lp), 16, 0, 0)

// Truncation hi/lo split: hi = top 16 bits, lo = top 16 bits of (v - hi).
static __device__ inline void split_bf(float v, short& hi, short& lo) {
  unsigned int b = __float_as_uint(v);
  unsigned int hb = b & 0xffff0000u;
  float lof = v - __uint_as_float(hb);
  hi = (short)(b >> 16);
  lo = (short)(__float_as_uint(lof) >> 16);
}

// Prep: thread per code. eT fp32 rows, cnorm, and the B image:
// [cc(32)][kh(2)][hi|lo][lane(64)*8] shorts (128 KB).
__global__ __launch_bounds__(256) void vq_prep(const float* __restrict__ emb,
                                               float* __restrict__ ws) {
  int c = blockIdx.x * 256 + threadIdx.x;  // 0..511
  unsigned short* img = (unsigned short*)(ws + WS_IMG);
  float* eT = ws + WS_ET;
  int cc = c >> 4;
  int n = c & 15;
  float cn = 0.f;
#pragma unroll
  for (int d0 = 0; d0 < DIM; d0 += 4) {
    float v[4];
#pragma unroll
    for (int u = 0; u < 4; ++u) {
      v[u] = emb[(d0 + u) * CODES + c];
      cn = fmaf(v[u], v[u], cn);
    }
    *(float4*)(eT + (size_t)c * DIM + d0) = make_float4(v[0], v[1], v[2], v[3]);
    int kh = d0 >> 5, kk = d0 & 31, qd = kk >> 3, j0 = kk & 7;
    int lane = qd * 16 + n;
    short hi[4], lo[4];
#pragma unroll
    for (int u = 0; u < 4; ++u) split_bf(v[u], hi[u], lo[u]);
    int base = cc * 2048 + kh * 1024 + lane * 8 + j0;
    *(ushort4*)(img + base) =
        make_ushort4((unsigned short)hi[0], (unsigned short)hi[1],
                     (unsigned short)hi[2], (unsigned short)hi[3]);
    *(ushort4*)(img + base + 512) =
        make_ushort4((unsigned short)lo[0], (unsigned short)lo[1],
                     (unsigned short)lo[2], (unsigned short)lo[3]);
  }
  ws[WS_CNORM + c] = cn;
}

// Fused screen + resolve + segment-sum. Block = 8 waves x 64 tokens.
// v3: B-image is streamed cc-chunk-by-chunk into a 12 KB rotating LDS window
// (3 x 4 KB, overlapping the phase-2 tile bytes -> LDS stays 71.8 KB, 2
// blocks/CU). Wave 0 issues global_load_lds with prefetch distance 2;
// per-cc sync is counted s_waitcnt vmcnt(4) + raw s_barrier (never vmcnt(0)
// in the steady loop), so staged loads stay in flight across barriers.
// This cuts per-block L2 image traffic 8x (2 MB -> 256 KB) and removes the
// per-wave L2-latency ping-pong stall that round-1 occupancy couldn't hide.
__global__ __launch_bounds__(512, 4) void vq_fused(
    const float* __restrict__ x, const float* __restrict__ ws,
    float* __restrict__ loss_sum, float* __restrict__ q_out,
    float* __restrict__ idx_out, float* __restrict__ part_base, int aflush,
    float* __restrict__ ws_acc) {
  __shared__ __align__(16) unsigned char smem[71808];
  float* lds_e = (float*)smem;              // phase-2 [32][513] tile, 65664 B
  float* lds_n = (float*)(smem + 65664);    // 512 counts
  float* cn_l = (float*)(smem + 67712);     // 512 code norms (persistent)
  int* win_l = (int*)(smem + 69760);        // 512 winner codes (persistent)
  // phase-1 staging window: bytes [0, 12288) of the (then-idle) lds_e region

  const float* eT = ws + WS_ET;
  const char* gib = (const char*)(ws + WS_IMG);

  for (int i = threadIdx.x; i < CODES; i += 512) cn_l[i] = ws[WS_CNORM + i];

  const int lane = threadIdx.x & 63;
  const int wave = threadIdx.x >> 6;
  const int n = lane & 15;
  const int quad = lane >> 4;
  const int t0 = blockIdx.x * 512 + wave * 64;

  const float INITP = __uint_as_float((__float_as_uint(1e30f) & 0xFFFFFE00u) | 511u);
  float loss = 0.f;

#pragma unroll 1
  for (int pair = 0; pair < 2; ++pair) {
    // A-fragments hi/lo of -2x for this pair's 2 token tiles
    bf16x8 ah[2][2], al[2][2];
#pragma unroll
    for (int tile = 0; tile < 2; ++tile) {
      const float* xr =
          x + (size_t)(t0 + (pair * 2 + tile) * 16 + n) * DIM + quad * 8;
#pragma unroll
      for (int kh = 0; kh < 2; ++kh) {
        float4 va = *(const float4*)(xr + kh * 32);
        float4 vb = *(const float4*)(xr + kh * 32 + 4);
        float f[8] = {va.x, va.y, va.z, va.w, vb.x, vb.y, vb.z, vb.w};
#pragma unroll
        for (int j = 0; j < 8; ++j) {
          short hi, lo;
          split_bf(-2.f * f[j], hi, lo);
          ah[tile][kh][j] = hi;
          al[tile][kh][j] = lo;
        }
      }
    }

    // packed (value|idx) top-2 registers
    float v1[2][4], v2[2][4];
#pragma unroll
    for (int tile = 0; tile < 2; ++tile)
#pragma unroll
      for (int r = 0; r < 4; ++r) {
        v1[tile][r] = INITP;
        v2[tile][r] = INITP;
      }

    // stage cc=0 and cc=1; __syncthreads drains wave-0's vmcnt fully (also
    // drains any epilogue stores from the previous pair on all waves, so the
    // in-loop vmcnt counts ONLY staging loads on wave 0).
    if (wave == 0) {
#pragma unroll
      for (int c0 = 0; c0 < 2; ++c0)
#pragma unroll
        for (int q = 0; q < 4; ++q)
          GLOAD_LDS16(gib + c0 * 4096 + q * 1024 + (size_t)lane * 16,
                      (char*)smem + c0 * 4096 + q * 1024);
    }
    __syncthreads();

#pragma unroll 1
    for (int cc = 0; cc < 32; ++cc) {
      const unsigned short* bp =
          (const unsigned short*)((const char*)smem + (cc % 3) * 4096);
      bf16x8 bh0 = *(const bf16x8*)(bp + lane * 8);
      bf16x8 bl0 = *(const bf16x8*)(bp + 512 + lane * 8);
      bf16x8 bh1 = *(const bf16x8*)(bp + 1024 + lane * 8);
      bf16x8 bl1 = *(const bf16x8*)(bp + 1536 + lane * 8);
      if (wave == 0 && cc < 30) {  // prefetch distance 2, no wrap stragglers
        char* lb = (char*)smem + ((cc + 2) % 3) * 4096;
        const char* gs = gib + (cc + 2) * 4096 + (size_t)lane * 16;
#pragma unroll
        for (int q = 0; q < 4; ++q) GLOAD_LDS16(gs + q * 1024, lb + q * 1024);
      }
      float cnv = cn_l[cc * 16 + n];
      unsigned int cid = (unsigned int)(cc * 16 + n);
#pragma unroll
      for (int tile = 0; tile < 2; ++tile) {
        f32x4 acc = {0.f, 0.f, 0.f, 0.f};
        acc = __builtin_amdgcn_mfma_f32_16x16x32_bf16(ah[tile][0], bh0, acc, 0, 0, 0);
        acc = __builtin_amdgcn_mfma_f32_16x16x32_bf16(al[tile][0], bh0, acc, 0, 0, 0);
        acc = __builtin_amdgcn_mfma_f32_16x16x32_bf16(ah[tile][0], bl0, acc, 0, 0, 0);
        acc = __builtin_amdgcn_mfma_f32_16x16x32_bf16(ah[tile][1], bh1, acc, 0, 0, 0);
        acc = __builtin_amdgcn_mfma_f32_16x16x32_bf16(al[tile][1], bh1, acc, 0, 0, 0);
        acc = __builtin_amdgcn_mfma_f32_16x16x32_bf16(ah[tile][1], bl1, acc, 0, 0, 0);
#pragma unroll
        for (int r = 0; r < 4; ++r) {
          float s = acc[r] + cnv;
          float sp = __uint_as_float((__float_as_uint(s) & 0xFFFFFE00u) | cid);
          float o1 = v1[tile][r];
          v2[tile][r] = __builtin_amdgcn_fmed3f(sp, o1, v2[tile][r]);
          v1[tile][r] = fminf(sp, o1);
        }
      }
      // counted wait: allow this iter's 4 staged loads (cc+2) to stay in
      // flight; require cc+1's resident before any wave crosses the barrier.
      if (cc < 30) {
        asm volatile("s_waitcnt vmcnt(4)" ::: "memory");
      } else {
        asm volatile("s_waitcnt vmcnt(0)" ::: "memory");
      }
      __builtin_amdgcn_sched_barrier(0);
      __builtin_amdgcn_s_barrier();
      __builtin_amdgcn_sched_barrier(0);
    }

    // butterfly top-2 merge across the quad's 16 lanes (packed floats)
#pragma unroll
    for (int m = 1; m < 16; m <<= 1) {
#pragma unroll
      for (int tile = 0; tile < 2; ++tile)
#pragma unroll
        for (int r = 0; r < 4; ++r) {
          float o1 = __shfl_xor(v1[tile][r], m, 16);
          float o2 = __shfl_xor(v2[tile][r], m, 16);
          float a = v1[tile][r];
          v1[tile][r] = fminf(a, o1);
          v2[tile][r] = fminf(fminf(v2[tile][r], o2), fmaxf(a, o1));
        }
    }

    // Exact fp32 epilogue for this pair's 2 tiles
#pragma unroll
    for (int tile = 0; tile < 2; ++tile) {
      int tt = pair * 2 + tile;
#pragma unroll
      for (int r = 0; r < 4; ++r) {
        int t = t0 + tt * 16 + quad * 4 + r;
        int c1 = (int)(__float_as_uint(v1[tile][r]) & 511u);
        int c2 = (int)(__float_as_uint(v2[tile][r]) & 511u);
        float4 xv = *(const float4*)(x + (size_t)t * DIM + n * 4);
        float4 e1 = *(const float4*)(eT + (size_t)c1 * DIM + n * 4);
        float4 e2 = *(const float4*)(eT + (size_t)c2 * DIM + n * 4);
        float p1 = xv.x * e1.x;
        p1 = fmaf(xv.y, e1.y, p1);
        p1 = fmaf(xv.z, e1.z, p1);
        p1 = fmaf(xv.w, e1.w, p1);
        float p2 = xv.x * e2.x;
        p2 = fmaf(xv.y, e2.y, p2);
        p2 = fmaf(xv.z, e2.z, p2);
        p2 = fmaf(xv.w, e2.w, p2);
#pragma unroll
        for (int m = 1; m < 16; m <<= 1) {
          p1 += __shfl_xor(p1, m, 16);
          p2 += __shfl_xor(p2, m, 16);
        }
        float d1 = fmaf(-2.f, p1, cn_l[c1]);
        float d2 = fmaf(-2.f, p2, cn_l[c2]);
        bool take2 = (d2 < d1) || (d2 == d1 && c2 < c1);
        int w = take2 ? c2 : c1;
        float4 q = take2 ? e2 : e1;
        *(float4*)(q_out + (size_t)t * DIM + n * 4) = q;
        float u0 = xv.x - q.x, u1 = xv.y - q.y;
        float u2 = xv.z - q.z, u3 = xv.w - q.w;
        loss = fmaf(u0, u0, loss);
        loss = fmaf(u1, u1, loss);
        loss = fmaf(u2, u2, loss);
        loss = fmaf(u3, u3, loss);
        if (n == 0) {
          idx_out[t] = (float)w;
          win_l[wave * 64 + tt * 16 + quad * 4 + r] = w;
        }
      }
    }
  }

#pragma unroll
  for (int off = 32; off > 0; off >>= 1) loss += __shfl_down(loss, off, 64);
  if (lane == 0) atomicAdd(loss_sum, loss);

  // ---- Phase 2: segment sum over this block's 512 tokens, kh-halves ----
  __syncthreads();  // all staging/stores drained (each wave's own counters)
  {
    float4 z = make_float4(0.f, 0.f, 0.f, 0.f);
    float4* zp = (float4*)smem;
    for (int i = threadIdx.x; i < 67712 / 16; i += 512) zp[i] = z;
  }
  __syncthreads();

#pragma unroll 1
  for (int kh = 0; kh < 2; ++kh) {
#pragma unroll
    for (int tile = 0; tile < 4; ++tile) {
      int wbi = win_l[wave * 64 + tile * 16 + n];
      if (kh == 0 && quad == 0) atomicAdd(&lds_n[wbi], 1.0f);
      const float* xr =
          x + (size_t)(t0 + tile * 16 + n) * DIM + kh * 32 + quad * 8;
      float4 xa = *(const float4*)(xr);
      float4 xb = *(const float4*)(xr + 4);
      int k0 = quad * 8;
      atomicAdd(&lds_e[(k0 + 0) * 513 + wbi], xa.x);
      atomicAdd(&lds_e[(k0 + 1) * 513 + wbi], xa.y);
      atomicAdd(&lds_e[(k0 + 2) * 513 + wbi], xa.z);
      atomicAdd(&lds_e[(k0 + 3) * 513 + wbi], xa.w);
      atomicAdd(&lds_e[(k0 + 4) * 513 + wbi], xb.x);
      atomicAdd(&lds_e[(k0 + 5) * 513 + wbi], xb.y);
      atomicAdd(&lds_e[(k0 + 6) * 513 + wbi], xb.z);
      atomicAdd(&lds_e[(k0 + 7) * 513 + wbi], xb.w);
    }
    __syncthreads();
    if (aflush) {
      if (kh == 0) {
        for (int i = threadIdx.x; i < CODES; i += 512) {
          float v = lds_n[i];
          if (v != 0.f) atomicAdd(&ws_acc[WS_NI + i], v);
        }
      }
      for (int i = threadIdx.x; i < 32 * CODES; i += 512) {
        int k = i >> 9, c = i & 511;
        float v = lds_e[k * 513 + c];
        if (v != 0.f) atomicAdd(&ws_acc[WS_EOFX + kh * 32 * CODES + i], v);
        if (kh == 0) lds_e[k * 513 + c] = 0.f;  // re-zero for the kh=1 pass
      }
    } else {
      float* dest = part_base + (size_t)blockIdx.x * PART_STRIDE;
      if (kh == 0) {
        for (int i = threadIdx.x; i < CODES; i += 512) dest[i] = lds_n[i];
      }
      for (int i = threadIdx.x; i < 32 * CODES; i += 512) {
        int k = i >> 9, c = i & 511;
        dest[CODES + kh * 32 * CODES + i] = lds_e[k * 513 + c];
        if (kh == 0) lds_e[k * 513 + c] = 0.f;  // re-zero for the kh=1 pass
      }
    }
    if (kh == 0) __syncthreads();
  }
}

// Reduction of NPART partials -> ws[WS_NI ..], p-dimension split 8 ways.
// Each (i, chunk) block sums 64 partials deterministically, then one
// atomicAdd per location (<=8 commutative fp32 contributions, ~1e-6 wobble).
__global__ __launch_bounds__(256) void vq_reduce(const float* __restrict__ part,
                                                 float* __restrict__ ws, int P) {
  int i = blockIdx.x * 256 + threadIdx.x;
  if (i >= PART_STRIDE) return;
  int cp = P >> 3;
  int p0 = blockIdx.y * cp;
  int pe = p0 + cp;
  float a0 = 0.f, a1 = 0.f, a2 = 0.f, a3 = 0.f;
  int p = p0;
  for (; p + 3 < pe; p += 4) {
    a0 += part[(size_t)(p + 0) * PART_STRIDE + i];
    a1 += part[(size_t)(p + 1) * PART_STRIDE + i];
    a2 += part[(size_t)(p + 2) * PART_STRIDE + i];
    a3 += part[(size_t)(p + 3) * PART_STRIDE + i];
  }
  for (; p < pe; ++p) a0 += part[(size_t)p * PART_STRIDE + i];
  atomicAdd(&ws[WS_NI + i], (a0 + a1) + (a2 + a3));
}

// EMA update + losses. Grid = DIM blocks, one thread per code.
__global__ __launch_bounds__(512) void vq_final(const float* __restrict__ Nin,
                                                const float* __restrict__ Min,
                                                const float* __restrict__ ws,
                                                float* __restrict__ out) {
  __shared__ float red[512];
  int c = threadIdx.x;
  int d = blockIdx.x;
  float niv = ws[WS_NI + c];
  float Nn = Nin[c] * DECAYF + OMDECAY * niv;
  red[c] = Nn;
  __syncthreads();
#pragma unroll
  for (int s = 256; s > 0; s >>= 1) {
    if (c < s) red[c] += red[c + s];
    __syncthreads();
  }
  float nsum = red[0];
  float Nsm = (Nn + EPSF) / (nsum + (float)CODES * EPSF) * nsum;
  float m = Min[d * CODES + c] * DECAYF + OMDECAY * ws[WS_EOFX + d * CODES + c];
  out[OFF_MNEW + d * CODES + c] = m;
  out[OFF_ENEW + d * CODES + c] = m / Nsm;
  if (d == 0) {
    out[OFF_NNEW + c] = Nn;
    if (c == 0) {
      float l = ws[WS_LOSS] / (float)XELEMS;
      out[OFF_QL] = l;
      out[OFF_CL] = l;
    }
  }
}

extern "C" void kernel_launch(void* const* d_in, const int* in_sizes, int n_in,
                              void* d_out, int out_size, void* d_ws, size_t ws_size,
                              hipStream_t stream) {
  const float* x = (const float*)d_in[0];
  const float* emb = (const float*)d_in[1];
  const float* Nin = (const float*)d_in[2];
  const float* Min = (const float*)d_in[3];
  float* out = (float*)d_out;
  float* ws = (float*)d_ws;

  size_t avail = ws_size / 4;
  int aflush = (avail < (size_t)WS_PART + (size_t)NPART * PART_STRIDE) ? 1 : 0;

  // zero ni/eofx/loss (reduce atomics + aflush path + loss all need it)
  hipMemsetAsync(ws + WS_NI, 0, (size_t)(WS_ET - WS_NI) * sizeof(float), stream);

  vq_prep<<<2, 256, 0, stream>>>(emb, ws);

  vq_fused<<<TOKENS / 512, 512, 0, stream>>>(
      x, ws, ws + WS_LOSS, out + OFF_Q, out + OFF_IDX, ws + WS_PART, aflush, ws);

  if (!aflush) {
    vq_reduce<<<dim3((PART_STRIDE + 255) / 256, 8), 256, 0, stream>>>(
        ws + WS_PART, ws, NPART);
  }

  vq_final<<<DIM, 512, 0, stream>>>(Nin, Min, ws, out);
}